// Round 9
// baseline (1549.630 us; speedup 1.0000x reference)
//
#include <hip/hip_runtime.h>
#include <hip/hip_bf16.h>
#include <cstddef>

#define NNODES 50000
#define NEDGES 800000
#define HID 128
#define NHEAD 8
#define SCAN_BLK 256
#define SCAN_NB ((NNODES + SCAN_BLK - 1) / SCAN_BLK)   // 196
#define AGG_NB (NNODES / 4)                            // 12500
#define NSLICE 32                                      // stats accumulator slices
#define SLAYER (NSLICE * 256 + 256)                    // floats per layer: slices + scale/shift

typedef __attribute__((ext_vector_type(8))) short short8;
typedef __attribute__((ext_vector_type(4))) float floatx4;

static inline size_t align_up(size_t x, size_t a) { return (x + a - 1) & ~(a - 1); }

__device__ inline unsigned short f2bf(float f) {
    unsigned u = __float_as_uint(f);
    unsigned r = (u + 0x7fffu + ((u >> 16) & 1u)) >> 16;
    return (unsigned short)r;
}
__device__ inline float bf_lo(unsigned int u) { return __uint_as_float(u << 16); }
__device__ inline float bf_hi(unsigned int u) { return __uint_as_float(u & 0xffff0000u); }
__device__ inline float bfu(unsigned short u) { return __uint_as_float(((unsigned int)u) << 16); }

// ---------------------------------------------------------------- init: wconv + zero-fill (1 dispatch)
__global__ __launch_bounds__(256) void init_kernel(const float* __restrict__ W1,
                                                   const float* __restrict__ W2,
                                                   const float* __restrict__ W3,
                                                   unsigned short* __restrict__ Wt,
                                                   int* __restrict__ zeroA, int nA,
                                                   float* __restrict__ zeroB, int nB) {
    int b = blockIdx.x;
    int t = threadIdx.x;
    if (b < 192) {
        int layer = b >> 6;
        const float* W = (layer == 0) ? W1 : ((layer == 1) ? W2 : W3);
        int idx = (b & 63) * 256 + t;   // k*128+n
        int n = idx & 127;
        int k = idx >> 7;
        Wt[layer * 16384 + n * 128 + k] = f2bf(W[idx]);
    } else {
        int nb = gridDim.x - 192;
        int bb = b - 192;
        for (int i = bb * 256 + t; i < nA; i += nb * 256) zeroA[i] = 0;
        for (int i = bb * 256 + t; i < nB; i += nb * 256) zeroB[i] = 0.f;
    }
}

// ---------------------------------------------------------------- CSR build
__global__ void hist_kernel(const int* __restrict__ edge, int* __restrict__ cnt) {
    int e = blockIdx.x * blockDim.x + threadIdx.x;
    if (e < NEDGES) {
        int d = edge[NEDGES + e];
        atomicAdd(&cnt[d], 1);
    }
}

__global__ __launch_bounds__(256) void scan_partial_kernel(const int* __restrict__ cnt,
                                                           int* __restrict__ bsum) {
    int t = threadIdx.x;
    int i = blockIdx.x * 256 + t;
    __shared__ int sm[256];
    sm[t] = (i < NNODES) ? cnt[i] : 0;
    __syncthreads();
    for (int off = 128; off > 0; off >>= 1) {
        if (t < off) sm[t] += sm[t + off];
        __syncthreads();
    }
    if (t == 0) bsum[blockIdx.x] = sm[0];
}

// emit with inline scan of the 196 block sums (saves the scan_bsum dispatch)
__global__ __launch_bounds__(256) void scan_emit_kernel(const int* __restrict__ cnt,
                                                        const int* __restrict__ bsum,
                                                        int* __restrict__ offs) {
    __shared__ int bs[256];
    __shared__ int sm[256];
    int t = threadIdx.x;
    bs[t] = (t < SCAN_NB) ? bsum[t] : 0;
    __syncthreads();
    for (int off = 1; off < 256; off <<= 1) {
        int x = (t >= off) ? bs[t - off] : 0;
        __syncthreads();
        bs[t] += x;
        __syncthreads();
    }
    int boff = (blockIdx.x == 0) ? 0 : bs[blockIdx.x - 1];
    int i = blockIdx.x * 256 + t;
    int v = (i < NNODES) ? cnt[i] : 0;
    sm[t] = v;
    __syncthreads();
    for (int off = 1; off < 256; off <<= 1) {
        int x = (t >= off) ? sm[t - off] : 0;
        __syncthreads();
        sm[t] += x;
        __syncthreads();
    }
    if (i < NNODES) offs[i] = boff + sm[t] - v;
    if (i == 0) offs[NNODES] = NEDGES;
}

__global__ void scatter_kernel(const int* __restrict__ edge, const int* __restrict__ offs,
                               int* __restrict__ cursor, int* __restrict__ csr,
                               int* __restrict__ dstpos) {
    int e = blockIdx.x * blockDim.x + threadIdx.x;
    if (e < NEDGES) {
        int s = edge[e];
        int d = edge[NEDGES + e];
        int p = offs[d] + atomicAdd(&cursor[d], 1);
        csr[p] = s;
        dstpos[p] = d;
    }
}

// ---------------------------------------------------------------- MFMA GEMM [N,128]x[128,128]
//   mode 0: X = Xin
//   mode 1: X = elu(bn(Xin; ss)); also write X to Hw (=h1, skip source)
//   mode 2: X = skip + elu(bn(Xin; ss))   (h3_in never materialized)
// ss = 256 floats: [0..128) scale, [128..256) shift (written by prev aggregate's last block)
#define GROWS 64
#define ASTRIDE 136
__global__ __launch_bounds__(256) void gemm_kernel(const float* __restrict__ Xin,
                                                   const float* __restrict__ skip,
                                                   const float* __restrict__ ss,
                                                   const unsigned short* __restrict__ Wt,
                                                   const float* __restrict__ a,
                                                   float* __restrict__ Hw,
                                                   unsigned short* __restrict__ Hb,
                                                   float* __restrict__ esrc,
                                                   float* __restrict__ edst,
                                                   int mode) {
    __shared__ unsigned short As[GROWS * ASTRIDE];   // A: [m][k]
    __shared__ unsigned short Bs[128 * ASTRIDE];     // B: [n][k]  (= W^T)
    int tid = threadIdx.x;
    int rowBase = blockIdx.x * GROWS;

    for (int i = tid; i < 128 * 16; i += 256) {
        int n = i >> 4, seg = i & 15;
        *(uint4*)(&Bs[n * ASTRIDE + seg * 8]) = *(const uint4*)(Wt + n * 128 + seg * 8);
    }

    {
        int r = tid >> 2;
        int cs = (tid & 3) * 32;
        int gr = rowBase + r;
        float4 vv[8];
        if (gr < NNODES) {
            #pragma unroll
            for (int j = 0; j < 8; ++j)
                vv[j] = *(const float4*)(Xin + (size_t)gr * HID + cs + j * 4);
            if (mode >= 1) {
                #pragma unroll
                for (int j = 0; j < 8; ++j) {
                    int ch = cs + j * 4;
                    float4 sc = *(const float4*)(ss + ch);
                    float4 sh = *(const float4*)(ss + 128 + ch);
                    float4 v = vv[j];
                    v.x = sc.x * v.x + sh.x;
                    v.y = sc.y * v.y + sh.y;
                    v.z = sc.z * v.z + sh.z;
                    v.w = sc.w * v.w + sh.w;
                    v.x = (v.x > 0.f) ? v.x : expm1f(v.x);
                    v.y = (v.y > 0.f) ? v.y : expm1f(v.y);
                    v.z = (v.z > 0.f) ? v.z : expm1f(v.z);
                    v.w = (v.w > 0.f) ? v.w : expm1f(v.w);
                    if (mode == 2) {
                        float4 s = *(const float4*)(skip + (size_t)gr * HID + ch);
                        v.x += s.x; v.y += s.y; v.z += s.z; v.w += s.w;
                    }
                    vv[j] = v;
                }
                if (mode == 1) {
                    #pragma unroll
                    for (int j = 0; j < 8; ++j)
                        *(float4*)(Hw + (size_t)gr * HID + cs + j * 4) = vv[j];
                }
            }
        } else {
            #pragma unroll
            for (int j = 0; j < 8; ++j) vv[j] = make_float4(0.f, 0.f, 0.f, 0.f);
        }
        unsigned int pk[16];
        #pragma unroll
        for (int j = 0; j < 8; ++j) {
            pk[2 * j]     = (unsigned int)f2bf(vv[j].x) | ((unsigned int)f2bf(vv[j].y) << 16);
            pk[2 * j + 1] = (unsigned int)f2bf(vv[j].z) | ((unsigned int)f2bf(vv[j].w) << 16);
        }
        #pragma unroll
        for (int q = 0; q < 4; ++q)
            *(uint4*)(&As[r * ASTRIDE + cs + q * 8]) =
                make_uint4(pk[4 * q], pk[4 * q + 1], pk[4 * q + 2], pk[4 * q + 3]);
    }
    __syncthreads();

    int wv = tid >> 6;
    int lane = tid & 63;
    int l15 = lane & 15;
    int quad = lane >> 4;
    const unsigned short* Arow = &As[(wv * 16 + l15) * ASTRIDE + quad * 8];
    short8 af[4];
    #pragma unroll
    for (int c = 0; c < 4; ++c) af[c] = *(const short8*)(Arow + c * 32);

    floatx4 acc[8];
    #pragma unroll
    for (int h = 0; h < 8; ++h) {
        acc[h] = (floatx4){0.f, 0.f, 0.f, 0.f};
        const unsigned short* Brow = &Bs[(h * 16 + l15) * ASTRIDE + quad * 8];
        #pragma unroll
        for (int c = 0; c < 4; ++c) {
            short8 bf = *(const short8*)(Brow + c * 32);
            acc[h] = __builtin_amdgcn_mfma_f32_16x16x32_bf16(af[c], bf, acc[h], 0, 0, 0);
        }
    }
    __syncthreads();

    #pragma unroll
    for (int h = 0; h < 8; ++h) {
        #pragma unroll
        for (int reg = 0; reg < 4; ++reg)
            As[(wv * 16 + quad * 4 + reg) * ASTRIDE + h * 16 + l15] = f2bf(acc[h][reg]);
    }
    __syncthreads();

    {
        int r = tid >> 2;
        int hp = tid & 3;                 // head pair
        int gr = rowBase + r;
        const unsigned short* row = &As[r * ASTRIDE + hp * 32];
        uint4 u[4];
        #pragma unroll
        for (int q = 0; q < 4; ++q) u[q] = *(const uint4*)(row + q * 8);
        if (gr < NNODES) {
            uint4* dst = (uint4*)(Hb + (size_t)gr * HID + hp * 32);
            #pragma unroll
            for (int q = 0; q < 4; ++q) dst[q] = u[q];
            float f[32];
            #pragma unroll
            for (int q = 0; q < 4; ++q) {
                unsigned int* pu = (unsigned int*)&u[q];
                #pragma unroll
                for (int j = 0; j < 4; ++j) {
                    f[q * 8 + 2 * j]     = bf_lo(pu[j]);
                    f[q * 8 + 2 * j + 1] = bf_hi(pu[j]);
                }
            }
            int h0 = hp * 2, h1 = hp * 2 + 1;
            float es0 = 0.f, ev0 = 0.f, es1 = 0.f, ev1 = 0.f;
            #pragma unroll
            for (int j = 0; j < 16; ++j) {
                es0 += f[j] * a[h0 * 32 + j];
                ev0 += f[j] * a[h0 * 32 + 16 + j];
                es1 += f[16 + j] * a[h1 * 32 + j];
                ev1 += f[16 + j] * a[h1 * 32 + 16 + j];
            }
            esrc[gr * NHEAD + h0] = es0;
            esrc[gr * NHEAD + h1] = es1;
            edst[gr * NHEAD + h0] = ev0;
            edst[gr * NHEAD + h1] = ev1;
        }
    }
}

// ---------------------------------------------------------------- edge weights
__global__ __launch_bounds__(256) void wedge_kernel(const int* __restrict__ csr,
                                                    const int* __restrict__ dstpos,
                                                    const float* __restrict__ esrc,
                                                    const float* __restrict__ edst,
                                                    unsigned short* __restrict__ wedge) {
    int idx = blockIdx.x * 256 + threadIdx.x;   // p*8 + h
    if (idx >= NEDGES * NHEAD) return;
    int h = idx & 7;
    int p = idx >> 3;
    int s = csr[p];
    int d = dstpos[p];
    float v = esrc[s * NHEAD + h] + edst[d * NHEAD + h];
    v = fmaxf(v, 0.2f * v);          // LeakyReLU
    wedge[idx] = f2bf(__expf(v));
}

// ---------------------------------------------------------------- softmax aggregation + fused BN
// One wave per node, 4 edge-slots x 16 channel-lanes: each lane loads a uint4
// (8 channels) of Hb per edge -> 6 VMEM/iter for 8 edges (vs 48/wave before).
// Cross-slot shfl butterfly once per wave. Stats: plain per-wave LDS rows ->
// sliced global atomics; LAST block (done counter) computes scale/shift.
__global__ __launch_bounds__(256) void aggregate_kernel(const int* __restrict__ offs,
                                                        const int* __restrict__ csr,
                                                        const unsigned short* __restrict__ wedge,
                                                        const unsigned short* __restrict__ Hb,
                                                        float* __restrict__ out,
                                                        float* __restrict__ statsPart,
                                                        int* __restrict__ done,
                                                        const float* __restrict__ g,
                                                        const float* __restrict__ b) {
    int tid = threadIdx.x;
    int wv = tid >> 6;
    int n = blockIdx.x * 4 + wv;
    int lane = tid & 63;
    int slot = lane >> 4;      // edge slot 0..3
    int sl = lane & 15;        // channel group: channels sl*8 .. sl*8+7
    int hp = sl >> 1;          // head owning those channels
    int beg = offs[n], end = offs[n + 1];

    float acc[8];
    #pragma unroll
    for (int j = 0; j < 8; ++j) acc[j] = 0.f;
    float den = 0.f;

    for (int i = beg; i < end; i += 8) {
        int k0 = i + slot, k1 = i + 4 + slot;
        int c0 = (k0 > end - 1) ? end - 1 : k0;
        int c1 = (k1 > end - 1) ? end - 1 : k1;
        int s0 = csr[c0];
        int s1 = csr[c1];
        unsigned short w0r = wedge[c0 * NHEAD + hp];
        unsigned short w1r = wedge[c1 * NHEAD + hp];
        uint4 h0 = *(const uint4*)(Hb + (size_t)s0 * HID + sl * 8);
        uint4 h1 = *(const uint4*)(Hb + (size_t)s1 * HID + sl * 8);
        float w0 = (k0 < end) ? bfu(w0r) : 0.f;
        float w1 = (k1 < end) ? bfu(w1r) : 0.f;
        den += w0 + w1;
        const unsigned int* p0 = (const unsigned int*)&h0;
        const unsigned int* p1 = (const unsigned int*)&h1;
        #pragma unroll
        for (int j = 0; j < 4; ++j) {
            acc[2 * j]     += w0 * bf_lo(p0[j]) + w1 * bf_lo(p1[j]);
            acc[2 * j + 1] += w0 * bf_hi(p0[j]) + w1 * bf_hi(p1[j]);
        }
    }

    // reduce across the 4 edge slots (lanes xor 16, 32)
    #pragma unroll
    for (int m = 16; m <= 32; m <<= 1) {
        den += __shfl_xor(den, m);
        #pragma unroll
        for (int j = 0; j < 8; ++j) acc[j] += __shfl_xor(acc[j], m);
    }
    float inv = 1.f / (den + 1e-16f);
    float o0 = acc[slot * 2] * inv;
    float o1 = acc[slot * 2 + 1] * inv;
    int ch = sl * 8 + slot * 2;
    *(float2*)(out + (size_t)n * HID + ch) = make_float2(o0, o1);

    // ---- BN partials: plain per-wave LDS rows, one barrier, sliced atomics
    __shared__ float sm[4][128];
    sm[wv][ch] = o0;
    sm[wv][ch + 1] = o1;
    __shared__ int lastflag;
    __syncthreads();
    if (tid < 128) {
        float a0 = sm[0][tid], a1 = sm[1][tid], a2 = sm[2][tid], a3 = sm[3][tid];
        float s = a0 + a1 + a2 + a3;
        float s2 = a0 * a0 + a1 * a1 + a2 * a2 + a3 * a3;
        float* slice = statsPart + (blockIdx.x & (NSLICE - 1)) * 256;
        atomicAdd(&slice[tid], s);
        atomicAdd(&slice[128 + tid], s2);
    }
    if (tid == 0) {
        __threadfence();
        int old = atomicAdd(done, 1);
        lastflag = (old == AGG_NB - 1) ? 1 : 0;
    }
    __syncthreads();
    if (lastflag) {
        __threadfence();
        if (tid < 128) {
            float s = 0.f, s2 = 0.f;
            for (int k = 0; k < NSLICE; ++k) {
                s  += __hip_atomic_load(&statsPart[k * 256 + tid], __ATOMIC_RELAXED,
                                        __HIP_MEMORY_SCOPE_AGENT);
                s2 += __hip_atomic_load(&statsPart[k * 256 + 128 + tid], __ATOMIC_RELAXED,
                                        __HIP_MEMORY_SCOPE_AGENT);
            }
            float mu = s / (float)NNODES;
            float var = s2 / (float)NNODES - mu * mu;
            float rstd = rsqrtf(var + 1e-5f);
            float scale = g[tid] * rstd;
            float* ssout = statsPart + NSLICE * 256;
            ssout[tid] = scale;
            ssout[128 + tid] = b[tid] - mu * scale;
        }
    }
}

__global__ void final_apply_kernel(const float* __restrict__ X, const float* __restrict__ ss,
                                   float* __restrict__ out) {
    int i = blockIdx.x * blockDim.x + threadIdx.x;
    int total4 = NNODES * HID / 4;
    if (i >= total4) return;
    float4 v = ((const float4*)X)[i];
    int c4 = (i & 31) * 4;
    float4 sc = *(const float4*)(ss + c4);
    float4 sh = *(const float4*)(ss + 128 + c4);
    v.x = sc.x * v.x + sh.x;
    v.y = sc.y * v.y + sh.y;
    v.z = sc.z * v.z + sh.z;
    v.w = sc.w * v.w + sh.w;
    ((float4*)out)[i] = v;
}

// ---------------------------------------------------------------- launch
extern "C" void kernel_launch(void* const* d_in, const int* in_sizes, int n_in,
                              void* d_out, int out_size, void* d_ws, size_t ws_size,
                              hipStream_t stream) {
    const float* x   = (const float*)d_in[0];
    const int* edge  = (const int*)d_in[1];
    const float* W1  = (const float*)d_in[2];
    const float* a1  = (const float*)d_in[3];
    const float* W2  = (const float*)d_in[4];
    const float* a2  = (const float*)d_in[5];
    const float* W3  = (const float*)d_in[6];
    const float* a3  = (const float*)d_in[7];
    const float* g1  = (const float*)d_in[8];
    const float* b1  = (const float*)d_in[9];
    const float* g2  = (const float*)d_in[10];
    const float* b2  = (const float*)d_in[11];
    const float* g3  = (const float*)d_in[12];
    const float* b3  = (const float*)d_in[13];
    float* outp      = (float*)d_out;

    char* p = (char*)d_ws;
    size_t cur = 0;
    auto carve = [&](size_t bytes) {
        void* r = p + cur;
        cur = align_up(cur + bytes, 256);
        return r;
    };
    int*   cnt    = (int*)carve(2 * NNODES * sizeof(int));   // cnt + cursor (zeroed together)
    int*   cursor = cnt + NNODES;
    int*   offs   = (int*)carve((NNODES + 1) * sizeof(int));
    int*   csr    = (int*)carve(NEDGES * sizeof(int));
    int*   dstpos = (int*)carve(NEDGES * sizeof(int));
    int*   bsum   = (int*)carve(SCAN_NB * sizeof(int));
    unsigned short* wt    = (unsigned short*)carve(3 * 16384 * sizeof(unsigned short));
    unsigned short* hb    = (unsigned short*)carve((size_t)NNODES * HID * sizeof(unsigned short));
    unsigned short* wedge = (unsigned short*)carve((size_t)NEDGES * NHEAD * sizeof(unsigned short));
    float* agg    = (float*)carve((size_t)NNODES * HID * sizeof(float));
    float* h1     = (float*)carve((size_t)NNODES * HID * sizeof(float));
    float* esrc   = (float*)carve((size_t)NNODES * NHEAD * sizeof(float));
    float* edst   = (float*)carve((size_t)NNODES * NHEAD * sizeof(float));
    float* stats  = (float*)carve((3 * SLAYER + 16) * sizeof(float));  // slices+scale/shift x3, done[] tail
    float* stats1 = stats;
    float* stats2 = stats + SLAYER;
    float* stats3 = stats + 2 * SLAYER;
    int*   done   = (int*)(stats + 3 * SLAYER);
    const float* ss1 = stats1 + NSLICE * 256;
    const float* ss2 = stats2 + NSLICE * 256;
    const float* ss3 = stats3 + NSLICE * 256;

    const int EB = (NEDGES + 255) / 256;
    const int GB = (NNODES + GROWS - 1) / GROWS;
    const int WB = (NEDGES * NHEAD + 255) / 256;
    const int PB = (NNODES * HID / 4 + 255) / 256;

    // ---- init (wconv + zero cnt/cursor/stats/done) + CSR build
    init_kernel<<<256, 256, 0, stream>>>(W1, W2, W3, wt,
                                         cnt, 2 * NNODES,
                                         stats, 3 * SLAYER + 16);
    hist_kernel<<<EB, 256, 0, stream>>>(edge, cnt);
    scan_partial_kernel<<<SCAN_NB, 256, 0, stream>>>(cnt, bsum);
    scan_emit_kernel<<<SCAN_NB, 256, 0, stream>>>(cnt, bsum, offs);
    scatter_kernel<<<EB, 256, 0, stream>>>(edge, offs, cursor, csr, dstpos);

    // ---- layer 1
    gemm_kernel<<<GB, 256, 0, stream>>>(x, nullptr, nullptr, wt, a1, nullptr, hb, esrc, edst, 0);
    wedge_kernel<<<WB, 256, 0, stream>>>(csr, dstpos, esrc, edst, wedge);
    aggregate_kernel<<<AGG_NB, 256, 0, stream>>>(offs, csr, wedge, hb, agg, stats1, done, g1, b1);

    // ---- layer 2
    gemm_kernel<<<GB, 256, 0, stream>>>(agg, nullptr, ss1, wt + 16384, a2, h1, hb, esrc, edst, 1);
    wedge_kernel<<<WB, 256, 0, stream>>>(csr, dstpos, esrc, edst, wedge);
    aggregate_kernel<<<AGG_NB, 256, 0, stream>>>(offs, csr, wedge, hb, agg, stats2, done + 1, g2, b2);

    // ---- layer 3
    gemm_kernel<<<GB, 256, 0, stream>>>(agg, h1, ss2, wt + 32768, a3, nullptr, hb, esrc, edst, 2);
    wedge_kernel<<<WB, 256, 0, stream>>>(csr, dstpos, esrc, edst, wedge);
    aggregate_kernel<<<AGG_NB, 256, 0, stream>>>(offs, csr, wedge, hb, agg, stats3, done + 2, g3, b3);
    final_apply_kernel<<<PB, 256, 0, stream>>>(agg, ss3, outp);
}

// Round 10
// 446.365 us; speedup vs baseline: 3.4717x; 3.4717x over previous
//
#include <hip/hip_runtime.h>
#include <hip/hip_bf16.h>
#include <cstddef>

#define NNODES 50000
#define NEDGES 800000
#define HID 128
#define NHEAD 8
#define SCAN_BLK 256
#define SCAN_NB ((NNODES + SCAN_BLK - 1) / SCAN_BLK)   // 196
#define AGG_NB (NNODES / 4)                            // 12500
#define NSLICE 64                                      // stats slices (R7/R8-proven contention level)
#define SLAYER (NSLICE * 512)                          // floats per layer of slice storage

typedef __attribute__((ext_vector_type(8))) short short8;
typedef __attribute__((ext_vector_type(4))) float floatx4;

static inline size_t align_up(size_t x, size_t a) { return (x + a - 1) & ~(a - 1); }

__device__ inline unsigned short f2bf(float f) {
    unsigned u = __float_as_uint(f);
    unsigned r = (u + 0x7fffu + ((u >> 16) & 1u)) >> 16;
    return (unsigned short)r;
}
__device__ inline float bf_lo(unsigned int u) { return __uint_as_float(u << 16); }
__device__ inline float bf_hi(unsigned int u) { return __uint_as_float(u & 0xffff0000u); }

// ---------------------------------------------------------------- init: wconv + all zero-fill (1 dispatch)
__global__ __launch_bounds__(256) void init_kernel(const float* __restrict__ W1,
                                                   const float* __restrict__ W2,
                                                   const float* __restrict__ W3,
                                                   unsigned short* __restrict__ Wt,
                                                   int* __restrict__ zeroA, int nA,
                                                   float* __restrict__ zeroB, int nB) {
    int b = blockIdx.x;
    int t = threadIdx.x;
    if (b < 192) {
        int layer = b >> 6;
        const float* W = (layer == 0) ? W1 : ((layer == 1) ? W2 : W3);
        int idx = (b & 63) * 256 + t;   // k*128+n
        int n = idx & 127;
        int k = idx >> 7;
        Wt[layer * 16384 + n * 128 + k] = f2bf(W[idx]);
    } else {
        int nb = gridDim.x - 192;
        int bb = b - 192;
        for (int i = bb * 256 + t; i < nA; i += nb * 256) zeroA[i] = 0;
        for (int i = bb * 256 + t; i < nB; i += nb * 256) zeroB[i] = 0.f;
    }
}

// ---------------------------------------------------------------- CSR build
__global__ void hist_kernel(const int* __restrict__ edge, int* __restrict__ cnt) {
    int e = blockIdx.x * blockDim.x + threadIdx.x;
    if (e < NEDGES) {
        int d = edge[NEDGES + e];
        atomicAdd(&cnt[d], 1);
    }
}

__global__ __launch_bounds__(256) void scan_partial_kernel(const int* __restrict__ cnt,
                                                           int* __restrict__ bsum) {
    int t = threadIdx.x;
    int i = blockIdx.x * 256 + t;
    __shared__ int sm[256];
    sm[t] = (i < NNODES) ? cnt[i] : 0;
    __syncthreads();
    for (int off = 128; off > 0; off >>= 1) {
        if (t < off) sm[t] += sm[t + off];
        __syncthreads();
    }
    if (t == 0) bsum[blockIdx.x] = sm[0];
}

// emit with inline scan of the 196 block sums (saves the scan_bsum dispatch; R9-proven)
__global__ __launch_bounds__(256) void scan_emit_kernel(const int* __restrict__ cnt,
                                                        const int* __restrict__ bsum,
                                                        int* __restrict__ offs) {
    __shared__ int bs[256];
    __shared__ int sm[256];
    int t = threadIdx.x;
    bs[t] = (t < SCAN_NB) ? bsum[t] : 0;
    __syncthreads();
    for (int off = 1; off < 256; off <<= 1) {
        int x = (t >= off) ? bs[t - off] : 0;
        __syncthreads();
        bs[t] += x;
        __syncthreads();
    }
    int boff = (blockIdx.x == 0) ? 0 : bs[blockIdx.x - 1];
    int i = blockIdx.x * 256 + t;
    int v = (i < NNODES) ? cnt[i] : 0;
    sm[t] = v;
    __syncthreads();
    for (int off = 1; off < 256; off <<= 1) {
        int x = (t >= off) ? sm[t - off] : 0;
        __syncthreads();
        sm[t] += x;
        __syncthreads();
    }
    if (i < NNODES) offs[i] = boff + sm[t] - v;
    if (i == 0) offs[NNODES] = NEDGES;
}

__global__ void scatter_kernel(const int* __restrict__ edge, const int* __restrict__ offs,
                               int* __restrict__ cursor, int* __restrict__ csr) {
    int e = blockIdx.x * blockDim.x + threadIdx.x;
    if (e < NEDGES) {
        int s = edge[e];
        int d = edge[NEDGES + e];
        int p = offs[d] + atomicAdd(&cursor[d], 1);
        csr[p] = s;
    }
}

// ---------------------------------------------------------------- MFMA GEMM [N,128]x[128,128]
//   mode 0: X = Xin
//   mode 1: X = elu(bn(Xin)); also write X to Hw (=h1, skip source)
//   mode 2: X = skip + elu(bn(Xin))   (h3_in never materialized)
// For mode>=1 the block first reduces the previous layer's 64 stat slices
// into LDS scale/shift (replaces the bn_finalize dispatch; ~64KB L2 reads).
#define GROWS 64
#define ASTRIDE 136
__global__ __launch_bounds__(256) void gemm_kernel(const float* __restrict__ Xin,
                                                   const float* __restrict__ skip,
                                                   const float* __restrict__ statsPart,
                                                   const float* __restrict__ g,
                                                   const float* __restrict__ b,
                                                   const unsigned short* __restrict__ Wt,
                                                   const float* __restrict__ a,
                                                   float* __restrict__ Hw,
                                                   unsigned short* __restrict__ Hb,
                                                   float* __restrict__ esrc,
                                                   float* __restrict__ edst,
                                                   int mode) {
    __shared__ unsigned short As[GROWS * ASTRIDE];   // A: [m][k]
    __shared__ unsigned short Bs[128 * ASTRIDE];     // B: [n][k]  (= W^T)
    __shared__ float ssm[256];                       // scale[128] | shift[128]
    int tid = threadIdx.x;
    int rowBase = blockIdx.x * GROWS;

    for (int i = tid; i < 128 * 16; i += 256) {
        int n = i >> 4, seg = i & 15;
        *(uint4*)(&Bs[n * ASTRIDE + seg * 8]) = *(const uint4*)(Wt + n * 128 + seg * 8);
    }

    if (mode >= 1) {
        if (tid < 128) {
            float s = 0.f, s2 = 0.f;
            #pragma unroll 8
            for (int k = 0; k < NSLICE; ++k) {
                s  += statsPart[k * 512 + tid];
                s2 += statsPart[k * 512 + 128 + tid];
            }
            float mu = s / (float)NNODES;
            float var = s2 / (float)NNODES - mu * mu;
            float rstd = rsqrtf(var + 1e-5f);
            float scale = g[tid] * rstd;
            ssm[tid] = scale;
            ssm[128 + tid] = b[tid] - mu * scale;
        }
        __syncthreads();   // mode is block-uniform
    }

    {
        int r = tid >> 2;
        int cs = (tid & 3) * 32;
        int gr = rowBase + r;
        float4 vv[8];
        if (gr < NNODES) {
            #pragma unroll
            for (int j = 0; j < 8; ++j)
                vv[j] = *(const float4*)(Xin + (size_t)gr * HID + cs + j * 4);
            if (mode >= 1) {
                #pragma unroll
                for (int j = 0; j < 8; ++j) {
                    int ch = cs + j * 4;
                    float4 sc = *(const float4*)(ssm + ch);
                    float4 sh = *(const float4*)(ssm + 128 + ch);
                    float4 v = vv[j];
                    v.x = sc.x * v.x + sh.x;
                    v.y = sc.y * v.y + sh.y;
                    v.z = sc.z * v.z + sh.z;
                    v.w = sc.w * v.w + sh.w;
                    v.x = (v.x > 0.f) ? v.x : expm1f(v.x);
                    v.y = (v.y > 0.f) ? v.y : expm1f(v.y);
                    v.z = (v.z > 0.f) ? v.z : expm1f(v.z);
                    v.w = (v.w > 0.f) ? v.w : expm1f(v.w);
                    if (mode == 2) {
                        float4 s = *(const float4*)(skip + (size_t)gr * HID + ch);
                        v.x += s.x; v.y += s.y; v.z += s.z; v.w += s.w;
                    }
                    vv[j] = v;
                }
                if (mode == 1) {
                    #pragma unroll
                    for (int j = 0; j < 8; ++j)
                        *(float4*)(Hw + (size_t)gr * HID + cs + j * 4) = vv[j];
                }
            }
        } else {
            #pragma unroll
            for (int j = 0; j < 8; ++j) vv[j] = make_float4(0.f, 0.f, 0.f, 0.f);
        }
        unsigned int pk[16];
        #pragma unroll
        for (int j = 0; j < 8; ++j) {
            pk[2 * j]     = (unsigned int)f2bf(vv[j].x) | ((unsigned int)f2bf(vv[j].y) << 16);
            pk[2 * j + 1] = (unsigned int)f2bf(vv[j].z) | ((unsigned int)f2bf(vv[j].w) << 16);
        }
        #pragma unroll
        for (int q = 0; q < 4; ++q)
            *(uint4*)(&As[r * ASTRIDE + cs + q * 8]) =
                make_uint4(pk[4 * q], pk[4 * q + 1], pk[4 * q + 2], pk[4 * q + 3]);
    }
    __syncthreads();

    int wv = tid >> 6;
    int lane = tid & 63;
    int l15 = lane & 15;
    int quad = lane >> 4;
    const unsigned short* Arow = &As[(wv * 16 + l15) * ASTRIDE + quad * 8];
    short8 af[4];
    #pragma unroll
    for (int c = 0; c < 4; ++c) af[c] = *(const short8*)(Arow + c * 32);

    floatx4 acc[8];
    #pragma unroll
    for (int h = 0; h < 8; ++h) {
        acc[h] = (floatx4){0.f, 0.f, 0.f, 0.f};
        const unsigned short* Brow = &Bs[(h * 16 + l15) * ASTRIDE + quad * 8];
        #pragma unroll
        for (int c = 0; c < 4; ++c) {
            short8 bf = *(const short8*)(Brow + c * 32);
            acc[h] = __builtin_amdgcn_mfma_f32_16x16x32_bf16(af[c], bf, acc[h], 0, 0, 0);
        }
    }
    __syncthreads();

    #pragma unroll
    for (int h = 0; h < 8; ++h) {
        #pragma unroll
        for (int reg = 0; reg < 4; ++reg)
            As[(wv * 16 + quad * 4 + reg) * ASTRIDE + h * 16 + l15] = f2bf(acc[h][reg]);
    }
    __syncthreads();

    {
        int r = tid >> 2;
        int hp = tid & 3;                 // head pair
        int gr = rowBase + r;
        const unsigned short* row = &As[r * ASTRIDE + hp * 32];
        uint4 u[4];
        #pragma unroll
        for (int q = 0; q < 4; ++q) u[q] = *(const uint4*)(row + q * 8);
        if (gr < NNODES) {
            uint4* dst = (uint4*)(Hb + (size_t)gr * HID + hp * 32);
            #pragma unroll
            for (int q = 0; q < 4; ++q) dst[q] = u[q];
            float f[32];
            #pragma unroll
            for (int q = 0; q < 4; ++q) {
                unsigned int* pu = (unsigned int*)&u[q];
                #pragma unroll
                for (int j = 0; j < 4; ++j) {
                    f[q * 8 + 2 * j]     = bf_lo(pu[j]);
                    f[q * 8 + 2 * j + 1] = bf_hi(pu[j]);
                }
            }
            int h0 = hp * 2, h1 = hp * 2 + 1;
            float es0 = 0.f, ev0 = 0.f, es1 = 0.f, ev1 = 0.f;
            #pragma unroll
            for (int j = 0; j < 16; ++j) {
                es0 += f[j] * a[h0 * 32 + j];
                ev0 += f[j] * a[h0 * 32 + 16 + j];
                es1 += f[16 + j] * a[h1 * 32 + j];
                ev1 += f[16 + j] * a[h1 * 32 + 16 + j];
            }
            esrc[gr * NHEAD + h0] = es0;
            esrc[gr * NHEAD + h1] = es1;
            edst[gr * NHEAD + h0] = ev0;
            edst[gr * NHEAD + h1] = ev1;
        }
    }
}

// ---------------------------------------------------------------- softmax aggregation + sliced BN stats
// R5's proven loop: one wave per node, 16-wide clamped batching, INLINE exp
// from esrc gather (57 us, VALU 75% measured). Epilogue: plain LDS rows ->
// 64-sliced global atomics (~195 same-address ops; R7/R8-proven). No done
// counter, no device fences (R6/R9 lesson).
__global__ __launch_bounds__(256) void aggregate_kernel(const int* __restrict__ offs,
                                                        const int* __restrict__ csr,
                                                        const float* __restrict__ esrc,
                                                        const float* __restrict__ edst,
                                                        const unsigned int* __restrict__ Hb,
                                                        float* __restrict__ out,
                                                        float* __restrict__ statsPart) {
    int tid = threadIdx.x;
    int wv = tid >> 6;
    int n = blockIdx.x * 4 + wv;
    int lane = tid & 63;       // owns channels 2*lane, 2*lane+1
    int head = lane >> 3;
    int beg = offs[n], end = offs[n + 1];
    float ed = edst[n * NHEAD + head];
    float acc0 = 0.f, acc1 = 0.f, den = 0.f;
    for (int i = beg; i < end; i += 16) {
        int ss[16];
        #pragma unroll
        for (int j = 0; j < 16; ++j) {
            int k = i + j;
            if (k > end - 1) k = end - 1;   // clamp: duplicate load, masked below
            ss[j] = csr[k];
        }
        float ee[16];
        unsigned int hh[16];
        #pragma unroll
        for (int j = 0; j < 16; ++j) ee[j] = esrc[ss[j] * NHEAD + head];
        #pragma unroll
        for (int j = 0; j < 16; ++j) hh[j] = Hb[(size_t)ss[j] * 64 + lane];
        #pragma unroll
        for (int j = 0; j < 16; ++j) {
            float e = ee[j] + ed;
            e = (e >= 0.f) ? e : 0.2f * e;
            float w = (i + j < end) ? __expf(e) : 0.f;
            den += w;
            acc0 += w * bf_lo(hh[j]);
            acc1 += w * bf_hi(hh[j]);
        }
    }
    float inv = 1.f / (den + 1e-16f);
    float o0 = acc0 * inv;
    float o1 = acc1 * inv;
    *(float2*)(out + (size_t)n * HID + lane * 2) = make_float2(o0, o1);

    // ---- BN partials: per-wave LDS rows (float2 store, 2-way alias = free),
    // one barrier, then 64-sliced global atomics.
    __shared__ float sm[4][128];
    *(float2*)(&sm[wv][lane * 2]) = make_float2(o0, o1);
    __syncthreads();
    if (tid < 128) {
        float a0 = sm[0][tid], a1 = sm[1][tid], a2 = sm[2][tid], a3 = sm[3][tid];
        float s = a0 + a1 + a2 + a3;
        float s2 = a0 * a0 + a1 * a1 + a2 * a2 + a3 * a3;
        float* slice = statsPart + (blockIdx.x & (NSLICE - 1)) * 512;
        atomicAdd(&slice[tid], s);
        atomicAdd(&slice[128 + tid], s2);
    }
}

// ---------------------------------------------------------------- final: reduce slices + apply BN
__global__ __launch_bounds__(256) void final_apply_kernel(const float* __restrict__ X,
                                                          const float* __restrict__ statsPart,
                                                          const float* __restrict__ g,
                                                          const float* __restrict__ b,
                                                          float* __restrict__ out) {
    __shared__ float ssm[256];
    int tid = threadIdx.x;
    if (tid < 128) {
        float s = 0.f, s2 = 0.f;
        #pragma unroll 8
        for (int k = 0; k < NSLICE; ++k) {
            s  += statsPart[k * 512 + tid];
            s2 += statsPart[k * 512 + 128 + tid];
        }
        float mu = s / (float)NNODES;
        float var = s2 / (float)NNODES - mu * mu;
        float rstd = rsqrtf(var + 1e-5f);
        float scale = g[tid] * rstd;
        ssm[tid] = scale;
        ssm[128 + tid] = b[tid] - mu * scale;
    }
    __syncthreads();
    int total4 = NNODES * HID / 4;
    for (int i = blockIdx.x * 256 + tid; i < total4; i += gridDim.x * 256) {
        float4 v = ((const float4*)X)[i];
        int c4 = (i & 31) * 4;
        float4 sc = *(const float4*)(ssm + c4);
        float4 sh = *(const float4*)(ssm + 128 + c4);
        v.x = sc.x * v.x + sh.x;
        v.y = sc.y * v.y + sh.y;
        v.z = sc.z * v.z + sh.z;
        v.w = sc.w * v.w + sh.w;
        ((float4*)out)[i] = v;
    }
}

// ---------------------------------------------------------------- launch (12 dispatches)
extern "C" void kernel_launch(void* const* d_in, const int* in_sizes, int n_in,
                              void* d_out, int out_size, void* d_ws, size_t ws_size,
                              hipStream_t stream) {
    const float* x   = (const float*)d_in[0];
    const int* edge  = (const int*)d_in[1];
    const float* W1  = (const float*)d_in[2];
    const float* a1  = (const float*)d_in[3];
    const float* W2  = (const float*)d_in[4];
    const float* a2  = (const float*)d_in[5];
    const float* W3  = (const float*)d_in[6];
    const float* a3  = (const float*)d_in[7];
    const float* g1  = (const float*)d_in[8];
    const float* b1  = (const float*)d_in[9];
    const float* g2  = (const float*)d_in[10];
    const float* b2  = (const float*)d_in[11];
    const float* g3  = (const float*)d_in[12];
    const float* b3  = (const float*)d_in[13];
    float* outp      = (float*)d_out;

    char* p = (char*)d_ws;
    size_t cur = 0;
    auto carve = [&](size_t bytes) {
        void* r = p + cur;
        cur = align_up(cur + bytes, 256);
        return r;
    };
    int*   cnt    = (int*)carve(2 * NNODES * sizeof(int));   // cnt + cursor (zeroed together)
    int*   cursor = cnt + NNODES;
    int*   offs   = (int*)carve((NNODES + 1) * sizeof(int));
    int*   csr    = (int*)carve(NEDGES * sizeof(int));
    int*   bsum   = (int*)carve(SCAN_NB * sizeof(int));
    unsigned short* wt = (unsigned short*)carve(3 * 16384 * sizeof(unsigned short));
    unsigned short* hb = (unsigned short*)carve((size_t)NNODES * HID * sizeof(unsigned short));
    float* agg    = (float*)carve((size_t)NNODES * HID * sizeof(float));
    float* h1     = (float*)carve((size_t)NNODES * HID * sizeof(float));
    float* esrc   = (float*)carve((size_t)NNODES * NHEAD * sizeof(float));
    float* edst   = (float*)carve((size_t)NNODES * NHEAD * sizeof(float));
    float* stats  = (float*)carve(3 * SLAYER * sizeof(float));   // 64 slices x 512 floats x 3 layers
    float* stats1 = stats;
    float* stats2 = stats + SLAYER;
    float* stats3 = stats + 2 * SLAYER;

    const int EB = (NEDGES + 255) / 256;
    const int GB = (NNODES + GROWS - 1) / GROWS;

    // ---- init (wconv + zero cnt/cursor + zero stats) + CSR build
    init_kernel<<<256, 256, 0, stream>>>(W1, W2, W3, wt,
                                         cnt, 2 * NNODES,
                                         stats, 3 * SLAYER);
    hist_kernel<<<EB, 256, 0, stream>>>(edge, cnt);
    scan_partial_kernel<<<SCAN_NB, 256, 0, stream>>>(cnt, bsum);
    scan_emit_kernel<<<SCAN_NB, 256, 0, stream>>>(cnt, bsum, offs);
    scatter_kernel<<<EB, 256, 0, stream>>>(edge, offs, cursor, csr);

    // ---- layer 1
    gemm_kernel<<<GB, 256, 0, stream>>>(x, nullptr, nullptr, nullptr, nullptr,
                                        wt, a1, nullptr, hb, esrc, edst, 0);
    aggregate_kernel<<<AGG_NB, 256, 0, stream>>>(offs, csr, esrc, edst,
                                                 (const unsigned int*)hb, agg, stats1);

    // ---- layer 2 (gemm reduces stats1 -> elu(bn1(agg)), writes h1)
    gemm_kernel<<<GB, 256, 0, stream>>>(agg, nullptr, stats1, g1, b1,
                                        wt + 16384, a2, h1, hb, esrc, edst, 1);
    aggregate_kernel<<<AGG_NB, 256, 0, stream>>>(offs, csr, esrc, edst,
                                                 (const unsigned int*)hb, agg, stats2);

    // ---- layer 3 (gemm reduces stats2 -> h1 + elu(bn2(agg)))
    gemm_kernel<<<GB, 256, 0, stream>>>(agg, h1, stats2, g2, b2,
                                        wt + 32768, a3, nullptr, hb, esrc, edst, 2);
    aggregate_kernel<<<AGG_NB, 256, 0, stream>>>(offs, csr, esrc, edst,
                                                 (const unsigned int*)hb, agg, stats3);

    // ---- final (reduces stats3 + applies bn3)
    final_apply_kernel<<<768, 256, 0, stream>>>(agg, stats3, g3, b3, outp);
}